// Round 4
// baseline (68.697 us; speedup 1.0000x reference)
//
#include <hip/hip_runtime.h>
#include <math.h>

// Chamfer distance: B=16, N=M=2048, D=3, fp32. Fused main kernel + tiny reduce.
// R3 post-mortem: model fits all rounds as {fill 40us + ~19-20us fixed graph
//   overhead + fused ~5us + sum ~1.5us}. Main-loop VALU floor is 3.4us; the
//   fused kernel's extra ~1.5us is the prologues: 48 scalar VMEM issues per
//   thread (24 opp staging + 24 src gather). This round vectorizes both:
//   - opp staging: 3 aligned float4 loads cover 4 interleaved xyz pts
//     (12-float deswizzle), 2 iters/thread -> 6 float4 instead of 24 scalars.
//     ds_write bank spread via (j + t>>3)&3 rotation.
//   - src gather: 8 consecutive pts = 24 floats = 6 aligned float4 loads
//     (offset 24*(chunk*8+c) floats = 96B-aligned).
//   Main loop, reduction, and sum kernel byte-identical to R3.
// Block = (combo, 64-src chunk), 1024 blocks = 4/CU (16 waves/CU).

typedef float v2f __attribute__((ext_vector_type(2)));

#define NPTS   2048
#define NCOMBO 32          // 2 dirs x 16 batches
#define SRCB   64          // src points per block
#define SPT    8           // src points per thread
#define NQ     32          // opp scan groups per block (256*SPT/SRCB)
#define OPPT   (NPTS/NQ)   // 64 opp points scanned per thread
#define NBLK   (NCOMBO * 32)
#define PAD(i) ((i) + (((i) >> 6) << 2))   // +4 words per 64 -> bank spread

__device__ __forceinline__ v2f pkfma(v2f a, v2f b, v2f c) {
#if __has_builtin(__builtin_elementwise_fma)
    return __builtin_elementwise_fma(a, b, c);
#else
    v2f d; d.x = fmaf(a.x, b.x, c.x); d.y = fmaf(a.y, b.y, c.y); return d;
#endif
}

__global__ __launch_bounds__(256, 2) void chamfer_fused(
    const float* __restrict__ preds,
    const float* __restrict__ tgts,
    float* __restrict__ bsum)
{
    __shared__ __align__(16) float qx[2176];   // 2048 + 128 pad words
    __shared__ __align__(16) float qy[2176];
    __shared__ __align__(16) float qz[2176];
    __shared__ __align__(16) float qw[2176];
    __shared__ float sm[4 * SRCB];             // per-wave partial minima

    const int combo = blockIdx.x & (NCOMBO - 1);
    const int chunk = blockIdx.x >> 5;         // 0..31
    const int dir   = combo >> 4;
    const int b     = combo & 15;

    const float* src = (dir ? tgts : preds) + (size_t)b * NPTS * 3;
    const float* opp = (dir ? preds : tgts) + (size_t)b * NPTS * 3;

    // Stage all 2048 opposing points (SoA, padded; |y|^2 in qw).
    // 3 float4 loads = 4 interleaved xyz points; 2 iters x 256 threads = 2048.
    const float4* opp4 = (const float4*)opp;
    #pragma unroll
    for (int p = 0; p < 2; p++) {
        const int t  = threadIdx.x + 256 * p;   // 0..511, pts 4t..4t+3
        const float4 A = opp4[3 * t + 0];
        const float4 B = opp4[3 * t + 1];
        const float4 C = opp4[3 * t + 2];
        const float xs[4] = {A.x, A.w, B.z, C.y};
        const float ys[4] = {A.y, B.x, B.w, C.z};
        const float zs[4] = {A.z, B.y, C.x, C.w};
        const int rot = (threadIdx.x >> 3) & 3;   // bank-spread rotation
        #pragma unroll
        for (int j = 0; j < 4; j++) {
            const int j2 = (j + rot) & 3;
            const int pi = PAD(4 * t + j2);
            const float x = xs[j2], y = ys[j2], z = zs[j2];
            qx[pi] = x;
            qy[pi] = y;
            qz[pi] = z;
            qw[pi] = x * x + y * y + z * z;
        }
    }

    const int q = threadIdx.x >> 3;   // opp range [64q, 64q+64)
    const int c = threadIdx.x & 7;    // src ownership group

    // 8 consecutive src points = 24 floats = 6 aligned float4 loads.
    float4 S[6];
    {
        const float4* s4 = (const float4*)(src + 3 * (chunk * SRCB + c * SPT));
        #pragma unroll
        for (int j = 0; j < 6; j++) S[j] = s4[j];
    }
    const float* sf = (const float*)S;

    // nn = -2*x duplicated for packed math
    v2f nn0[SPT], nn1[SPT], nn2[SPT];
    float m[SPT];
    #pragma unroll
    for (int k = 0; k < SPT; k++) {
        const float a0 = -2.0f * sf[3 * k + 0];
        const float a1 = -2.0f * sf[3 * k + 1];
        const float a2 = -2.0f * sf[3 * k + 2];
        nn0[k] = (v2f){a0, a0};
        nn1[k] = (v2f){a1, a1};
        nn2[k] = (v2f){a2, a2};
        m[k]   = INFINITY;
    }
    __syncthreads();

    const int base = q * 68;          // PAD(q*64); 16B-aligned
    #pragma unroll 1
    for (int g = 0; g < OPPT / 4; g++) {
        const float4 X = *(const float4*)&qx[base + 4 * g];
        const float4 Y = *(const float4*)&qy[base + 4 * g];
        const float4 Z = *(const float4*)&qz[base + 4 * g];
        const float4 W = *(const float4*)&qw[base + 4 * g];
        const v2f Xa = {X.x, X.y}, Xb = {X.z, X.w};
        const v2f Ya = {Y.x, Y.y}, Yb = {Y.z, Y.w};
        const v2f Za = {Z.x, Z.y}, Zb = {Z.z, Z.w};
        const v2f Wa = {W.x, W.y}, Wb = {W.z, W.w};
        #pragma unroll
        for (int k = 0; k < SPT; k++) {
            const v2f sa = pkfma(nn0[k], Xa, pkfma(nn1[k], Ya, pkfma(nn2[k], Za, Wa)));
            m[k] = fminf(fminf(m[k], sa.x), sa.y);        // v_min3_f32
            const v2f sb = pkfma(nn0[k], Xb, pkfma(nn1[k], Yb, pkfma(nn2[k], Zb, Wb)));
            m[k] = fminf(fminf(m[k], sb.x), sb.y);        // v_min3_f32
        }
    }

    // Min over the 32 q-groups: 8 in-wave q's via shfl_xor (bits 3..5 of lane),
    // then the 4 waves via 1KB LDS.
    #pragma unroll
    for (int k = 0; k < SPT; k++) {
        float v = m[k];
        v = fminf(v, __shfl_xor(v, 8, 64));
        v = fminf(v, __shfl_xor(v, 16, 64));
        v = fminf(v, __shfl_xor(v, 32, 64));
        m[k] = v;
    }
    const int lane = threadIdx.x & 63;
    const int wid  = threadIdx.x >> 6;
    if (lane < 8) {
        #pragma unroll
        for (int k = 0; k < SPT; k++)
            sm[wid * SRCB + c * SPT + k] = m[k];
    }
    __syncthreads();

    // Wave 0: finalize 64 src minima, add |x|^2, block-sum, ONE plain store.
    if (threadIdx.x < 64) {
        const int off = (threadIdx.x & 7) * SPT + (threadIdx.x >> 3);
        float mn = fminf(fminf(sm[off],            sm[SRCB + off]),
                         fminf(sm[2 * SRCB + off], sm[3 * SRCB + off]));
        const int s = chunk * SRCB + off;
        const float x0 = src[3 * s + 0];
        const float x1 = src[3 * s + 1];
        const float x2 = src[3 * s + 2];
        float val = x0 * x0 + x1 * x1 + x2 * x2 + mn;
        #pragma unroll
        for (int o = 32; o > 0; o >>= 1)
            val += __shfl_down(val, o, 64);
        if (threadIdx.x == 0) bsum[blockIdx.x] = val;
    }
}

__global__ __launch_bounds__(256) void chamfer_sum(
    const float* __restrict__ bsum,
    float* __restrict__ out)
{
    __shared__ float wsum[4];

    float val = bsum[threadIdx.x]         + bsum[threadIdx.x + 256]
              + bsum[threadIdx.x + 512]   + bsum[threadIdx.x + 768];

    #pragma unroll
    for (int o = 32; o > 0; o >>= 1)
        val += __shfl_down(val, o, 64);

    const int lane = threadIdx.x & 63;
    const int wid  = threadIdx.x >> 6;
    if (lane == 0) wsum[wid] = val;
    __syncthreads();
    if (threadIdx.x == 0)
        out[0] = wsum[0] + wsum[1] + wsum[2] + wsum[3];
}

extern "C" void kernel_launch(void* const* d_in, const int* in_sizes, int n_in,
                              void* d_out, int out_size, void* d_ws, size_t ws_size,
                              hipStream_t stream) {
    const float* preds = (const float*)d_in[0];
    const float* tgts  = (const float*)d_in[1];
    float* out  = (float*)d_out;
    float* bsum = (float*)d_ws;   // 1024 floats

    chamfer_fused<<<NBLK, 256, 0, stream>>>(preds, tgts, bsum);
    chamfer_sum<<<1, 256, 0, stream>>>(bsum, out);
}

// Round 5
// 66.869 us; speedup vs baseline: 1.0273x; 1.0273x over previous
//
#include <hip/hip_runtime.h>
#include <math.h>

// Chamfer distance: B=16, N=M=2048, D=3, fp32. Fused main kernel + tiny reduce.
// R4 post-mortem: the vectorized staging regressed (65.7 -> 68.7) because the
//   deswizzle arrays were indexed with a RUNTIME rotation (rule #20) -> scratch
//   (~50 MB of spill traffic ~= +3us). This round keeps the float4 loads but
//   deswizzles with fully STATIC component names (point1 = A.w,B.x,B.y, ...)
//   and drops the rotation. ds_writes are 8-way bank-conflicted (stride-4),
//   a one-time ~0.15us staging cost; the hot read path's conflict-free padded
//   layout is untouched.
// Block = (combo, 64-src chunk), 1024 blocks = 4/CU (16 waves/CU).
// Thread owns SPT=8 src pts (regs, 6 aligned float4 loads), scans 64 opp pts
//   => 2 VALU ops/pair (pk_fma + min3) with 8x LDS-read amortization.

typedef float v2f __attribute__((ext_vector_type(2)));

#define NPTS   2048
#define NCOMBO 32          // 2 dirs x 16 batches
#define SRCB   64          // src points per block
#define SPT    8           // src points per thread
#define NQ     32          // opp scan groups per block (256*SPT/SRCB)
#define OPPT   (NPTS/NQ)   // 64 opp points scanned per thread
#define NBLK   (NCOMBO * 32)
#define PAD(i) ((i) + (((i) >> 6) << 2))   // +4 words per 64 -> bank spread

__device__ __forceinline__ v2f pkfma(v2f a, v2f b, v2f c) {
#if __has_builtin(__builtin_elementwise_fma)
    return __builtin_elementwise_fma(a, b, c);
#else
    v2f d; d.x = fmaf(a.x, b.x, c.x); d.y = fmaf(a.y, b.y, c.y); return d;
#endif
}

__global__ __launch_bounds__(256, 2) void chamfer_fused(
    const float* __restrict__ preds,
    const float* __restrict__ tgts,
    float* __restrict__ bsum)
{
    __shared__ __align__(16) float qx[2176];   // 2048 + 128 pad words
    __shared__ __align__(16) float qy[2176];
    __shared__ __align__(16) float qz[2176];
    __shared__ __align__(16) float qw[2176];
    __shared__ float sm[4 * SRCB];             // per-wave partial minima

    const int combo = blockIdx.x & (NCOMBO - 1);
    const int chunk = blockIdx.x >> 5;         // 0..31
    const int dir   = combo >> 4;
    const int b     = combo & 15;

    const float* src = (dir ? tgts : preds) + (size_t)b * NPTS * 3;
    const float* opp = (dir ? preds : tgts) + (size_t)b * NPTS * 3;

    // Stage all 2048 opposing points (SoA, padded; |y|^2 in qw).
    // 3 float4 loads = 4 interleaved xyz points, STATIC deswizzle (no scratch).
    const float4* opp4 = (const float4*)opp;
    #pragma unroll
    for (int p = 0; p < 2; p++) {
        const int t  = threadIdx.x + 256 * p;   // pts 4t..4t+3
        const float4 A = opp4[3 * t + 0];       // x0 y0 z0 x1
        const float4 B = opp4[3 * t + 1];       // y1 z1 x2 y2
        const float4 C = opp4[3 * t + 2];       // z2 x3 y3 z3
        const int i0 = 4 * t;
        {   const int pi = PAD(i0 + 0);
            qx[pi] = A.x; qy[pi] = A.y; qz[pi] = A.z;
            qw[pi] = A.x * A.x + A.y * A.y + A.z * A.z; }
        {   const int pi = PAD(i0 + 1);
            qx[pi] = A.w; qy[pi] = B.x; qz[pi] = B.y;
            qw[pi] = A.w * A.w + B.x * B.x + B.y * B.y; }
        {   const int pi = PAD(i0 + 2);
            qx[pi] = B.z; qy[pi] = B.w; qz[pi] = C.x;
            qw[pi] = B.z * B.z + B.w * B.w + C.x * C.x; }
        {   const int pi = PAD(i0 + 3);
            qx[pi] = C.y; qy[pi] = C.z; qz[pi] = C.w;
            qw[pi] = C.y * C.y + C.z * C.z + C.w * C.w; }
    }

    const int q = threadIdx.x >> 3;   // opp range [64q, 64q+64)
    const int c = threadIdx.x & 7;    // src ownership group

    // 8 consecutive src points = 24 floats = 6 aligned float4 loads.
    float4 S[6];
    {
        const float4* s4 = (const float4*)(src + 3 * (chunk * SRCB + c * SPT));
        #pragma unroll
        for (int j = 0; j < 6; j++) S[j] = s4[j];
    }
    const float* sf = (const float*)S;

    // nn = -2*x duplicated for packed math
    v2f nn0[SPT], nn1[SPT], nn2[SPT];
    float m[SPT];
    #pragma unroll
    for (int k = 0; k < SPT; k++) {             // k static -> sf[] static
        const float a0 = -2.0f * sf[3 * k + 0];
        const float a1 = -2.0f * sf[3 * k + 1];
        const float a2 = -2.0f * sf[3 * k + 2];
        nn0[k] = (v2f){a0, a0};
        nn1[k] = (v2f){a1, a1};
        nn2[k] = (v2f){a2, a2};
        m[k]   = INFINITY;
    }
    __syncthreads();

    const int base = q * 68;          // PAD(q*64); 16B-aligned
    #pragma unroll 1
    for (int g = 0; g < OPPT / 4; g++) {
        const float4 X = *(const float4*)&qx[base + 4 * g];
        const float4 Y = *(const float4*)&qy[base + 4 * g];
        const float4 Z = *(const float4*)&qz[base + 4 * g];
        const float4 W = *(const float4*)&qw[base + 4 * g];
        const v2f Xa = {X.x, X.y}, Xb = {X.z, X.w};
        const v2f Ya = {Y.x, Y.y}, Yb = {Y.z, Y.w};
        const v2f Za = {Z.x, Z.y}, Zb = {Z.z, Z.w};
        const v2f Wa = {W.x, W.y}, Wb = {W.z, W.w};
        #pragma unroll
        for (int k = 0; k < SPT; k++) {
            const v2f sa = pkfma(nn0[k], Xa, pkfma(nn1[k], Ya, pkfma(nn2[k], Za, Wa)));
            m[k] = fminf(fminf(m[k], sa.x), sa.y);        // v_min3_f32
            const v2f sb = pkfma(nn0[k], Xb, pkfma(nn1[k], Yb, pkfma(nn2[k], Zb, Wb)));
            m[k] = fminf(fminf(m[k], sb.x), sb.y);        // v_min3_f32
        }
    }

    // Min over the 32 q-groups: 8 in-wave q's via shfl_xor (bits 3..5 of lane),
    // then the 4 waves via 1KB LDS.
    #pragma unroll
    for (int k = 0; k < SPT; k++) {
        float v = m[k];
        v = fminf(v, __shfl_xor(v, 8, 64));
        v = fminf(v, __shfl_xor(v, 16, 64));
        v = fminf(v, __shfl_xor(v, 32, 64));
        m[k] = v;
    }
    const int lane = threadIdx.x & 63;
    const int wid  = threadIdx.x >> 6;
    if (lane < 8) {
        #pragma unroll
        for (int k = 0; k < SPT; k++)
            sm[wid * SRCB + c * SPT + k] = m[k];
    }
    __syncthreads();

    // Wave 0: finalize 64 src minima, add |x|^2, block-sum, ONE plain store.
    if (threadIdx.x < 64) {
        const int off = (threadIdx.x & 7) * SPT + (threadIdx.x >> 3);
        float mn = fminf(fminf(sm[off],            sm[SRCB + off]),
                         fminf(sm[2 * SRCB + off], sm[3 * SRCB + off]));
        const int s = chunk * SRCB + off;
        const float x0 = src[3 * s + 0];
        const float x1 = src[3 * s + 1];
        const float x2 = src[3 * s + 2];
        float val = x0 * x0 + x1 * x1 + x2 * x2 + mn;
        #pragma unroll
        for (int o = 32; o > 0; o >>= 1)
            val += __shfl_down(val, o, 64);
        if (threadIdx.x == 0) bsum[blockIdx.x] = val;
    }
}

__global__ __launch_bounds__(256) void chamfer_sum(
    const float* __restrict__ bsum,
    float* __restrict__ out)
{
    __shared__ float wsum[4];

    float val = bsum[threadIdx.x]         + bsum[threadIdx.x + 256]
              + bsum[threadIdx.x + 512]   + bsum[threadIdx.x + 768];

    #pragma unroll
    for (int o = 32; o > 0; o >>= 1)
        val += __shfl_down(val, o, 64);

    const int lane = threadIdx.x & 63;
    const int wid  = threadIdx.x >> 6;
    if (lane == 0) wsum[wid] = val;
    __syncthreads();
    if (threadIdx.x == 0)
        out[0] = wsum[0] + wsum[1] + wsum[2] + wsum[3];
}

extern "C" void kernel_launch(void* const* d_in, const int* in_sizes, int n_in,
                              void* d_out, int out_size, void* d_ws, size_t ws_size,
                              hipStream_t stream) {
    const float* preds = (const float*)d_in[0];
    const float* tgts  = (const float*)d_in[1];
    float* out  = (float*)d_out;
    float* bsum = (float*)d_ws;   // 1024 floats

    chamfer_fused<<<NBLK, 256, 0, stream>>>(preds, tgts, bsum);
    chamfer_sum<<<1, 256, 0, stream>>>(bsum, out);
}